// Round 12
// baseline (104.727 us; speedup 1.0000x reference)
//
#include <hip/hip_runtime.h>
#include <hip/hip_bf16.h>

// Problem constants
#define NN    4096
#define INS_  256
#define OUTS_ 64
#define MM    4
#define LOG2E 1.4426950408889634f

typedef float f32x4 __attribute__((ext_vector_type(4)));
typedef short s16x8 __attribute__((ext_vector_type(8)));
typedef unsigned int u32x4 __attribute__((ext_vector_type(4)));

typedef const __attribute__((address_space(1))) unsigned char glob_u8;
typedef __attribute__((address_space(3))) unsigned char lds_u8;

__device__ __forceinline__ void stage16(const void* g, void* l) {
    __builtin_amdgcn_global_load_lds((glob_u8*)g, (lds_u8*)l, 16, 0, 0);
}

__device__ __forceinline__ unsigned int cvt_pk_bf16(float a, float b) {
    unsigned int r;
    asm("v_cvt_pk_bf16_f32 %0, %1, %2" : "=v"(r) : "v"(a), "v"(b));
    return r;
}

// pack two f32 into bf16x2 (RNE) - VALU fallback used in k_filmc (not hot)
__device__ __forceinline__ unsigned int pack_bf16(float a, float b) {
    unsigned int ua = __builtin_bit_cast(unsigned int, a);
    unsigned int ub = __builtin_bit_cast(unsigned int, b);
    ua = (ua + 0x7FFFu + ((ua >> 16) & 1u)) >> 16;
    ub = (ub + 0x7FFFu + ((ub >> 16) & 1u)) & 0xFFFF0000u;
    return ua | ub;
}

// keep w if bit e of mb set, else 0  (sign-extend bit + and)
__device__ __forceinline__ float mand(float w, unsigned mb, int e) {
    const int m = ((int)(mb << (31 - e))) >> 31;
    return __builtin_bit_cast(float, (__builtin_bit_cast(int, w) & m));
}

// build A-fragment: 8 weights max(P, c*Q) masked, packed to bf16; accumulate f32 Z
__device__ __forceinline__ s16x8 mk_af(float c, unsigned mb,
        const f32x4 q0, const f32x4 q1, const f32x4 q2, const f32x4 q3, float& z) {
    const float w0 = mand(fmaxf(q0[0], c * q0[1]), mb, 0);
    const float w1 = mand(fmaxf(q0[2], c * q0[3]), mb, 1);
    const float w2 = mand(fmaxf(q1[0], c * q1[1]), mb, 2);
    const float w3 = mand(fmaxf(q1[2], c * q1[3]), mb, 3);
    const float w4 = mand(fmaxf(q2[0], c * q2[1]), mb, 4);
    const float w5 = mand(fmaxf(q2[2], c * q2[3]), mb, 5);
    const float w6 = mand(fmaxf(q3[0], c * q3[1]), mb, 6);
    const float w7 = mand(fmaxf(q3[2], c * q3[3]), mb, 7);
    z += ((w0 + w1) + (w2 + w3)) + ((w4 + w5) + (w6 + w7));
    u32x4 au;
    au.x = cvt_pk_bf16(w0, w1);
    au.y = cvt_pk_bf16(w2, w3);
    au.z = cvt_pk_bf16(w4, w5);
    au.w = cvt_pk_bf16(w6, w7);
    return __builtin_bit_cast(s16x8, au);
}

// ws layout (floats):
//   [0,16384)       part float [64][256]  (partial column sums)
//   [16896,33280)   sc  float [M][N]   = V/U = 2^{-0.8 s'}
//   [33280,66048)   spq float2[M][N]   = {2^{d'}, 2^{0.2 d'}}
//   byte 264192     Ht bf16 tiles [m][jt=0..127][4KB]: tile(o,jj) at o*64+jj*2  (2 MB)
//   byte 2361344    adj bitmask [N][512B]                                       (2 MB)

// ---------- kernel 1: fused adj->bitmask pack (blocks 0..1023) + x column
//            partial sums (blocks 1024..1087) ----------
__global__ __launch_bounds__(256) void k_prep(const int* __restrict__ adj,
                                              unsigned long long* __restrict__ msk,
                                              const float* __restrict__ x,
                                              float* __restrict__ part) {
    const int b = blockIdx.x;
    if (b < 1024) {
        const int lane = threadIdx.x & 63;
        const int w    = threadIdx.x >> 6;
        const int r    = b * 4 + w;
        const int* __restrict__ row = adj + (size_t)r * NN;
        unsigned long long* mrow = msk + (size_t)r * 64;
        #pragma unroll 1
        for (int c0 = 0; c0 < 64; c0 += 16) {
            int a[16];
            #pragma unroll
            for (int k = 0; k < 16; ++k) a[k] = row[(c0 + k) * 64 + lane];
            unsigned long long m[16];
            #pragma unroll
            for (int k = 0; k < 16; ++k) m[k] = __ballot(a[k] != 0);
            if (lane == 0) {
                #pragma unroll
                for (int k = 0; k < 16; ++k) mrow[c0 + k] = m[k];
            }
        }
    } else {
        const int bb = b - 1024;
        const int t  = threadIdx.x;
        const int r0 = bb * 64;
        float s = 0.f;
        #pragma unroll 8
        for (int r = 0; r < 64; ++r) s += x[(size_t)(r0 + r) * INS_ + t];
        part[bb * INS_ + t] = s;
    }
}

// ---------- kernel 2: fused conditioner + FiLM; emit tiled Ht, sc, spq ----------
__global__ __launch_bounds__(256, 2) void k_filmc(
    const float* __restrict__ x, const float* __restrict__ W,
    const float* __restrict__ a1, const float* __restrict__ a2,
    const float* __restrict__ part, const float* __restrict__ Wc,
    const float* __restrict__ bc, float* __restrict__ sc,
    float* __restrict__ spq, unsigned char* __restrict__ htb)
{
    __shared__ float wlds[INS_ * OUTS_];     // 64 KB: W[m] as [i][o]
    __shared__ float sp[INS_];
    __shared__ float pg[256];
    __shared__ float gg[64], bbv[64];

    const int t  = threadIdx.x;
    const int o  = t & 63;
    const int wv = __builtin_amdgcn_readfirstlane(t >> 6);   // wave 0..3
    const int m  = blockIdx.y;
    const int n0 = blockIdx.x * 32 + wv * 8;                 // this wave's 8 rows

    // async-stage W[m] (64 KB) into LDS: 16 x (256 thr x 16B)
    {
        const unsigned char* wsrc = (const unsigned char*)W + (size_t)m * 65536 + t * 16;
        unsigned char* wdst = (unsigned char*)wlds + t * 16;
        #pragma unroll
        for (int it = 0; it < 16; ++it)
            stage16(wsrc + it * 4096, wdst + it * 4096);
    }

    // conditioner: reduce partial column sums (all 256 threads)
    {
        float s = 0.f;
        #pragma unroll 8
        for (int b = 0; b < 64; ++b) s += part[b * INS_ + t];
        sp[t] = s * (1.0f / NN);
    }
    __syncthreads();   // sp ready (also drains W staging vmcnt)

    // split-K conditioner dot: 256 threads cover 128 outputs x 2 K-halves
    {
        const int half = t >> 7;            // 0/1
        const int idx  = t & 127;           // output index
        const int col  = m * 64 + (idx & 63) + ((idx & 64) ? 256 : 0);
        float acc = (half == 0) ? bc[col] : 0.f;
        const int ib = half * 128;
        #pragma unroll 8
        for (int i = 0; i < 128; ++i)
            acc = fmaf(sp[ib + i], Wc[(size_t)(ib + i) * 512 + col], acc);
        pg[t] = acc;
    }
    __syncthreads();
    if (t < 128) {
        const float v = pg[t] + pg[t + 128];
        if (t < 64) gg[t] = v; else bbv[t - 64] = v;
    }
    __syncthreads();

    // main x@W loop: wl from LDS (conflict-free), x rows via scalar loads
    float acc[8];
    #pragma unroll
    for (int k = 0; k < 8; ++k) acc[k] = 0.f;

    const float* xp = x + (size_t)n0 * INS_;

    #pragma unroll 4
    for (int i = 0; i < INS_; ++i) {
        const float wl = wlds[i * 64 + o];
        #pragma unroll
        for (int k = 0; k < 8; ++k)
            acc[k] = fmaf(xp[k * INS_ + i], wl, acc[k]);
    }

    const float ga  = gg[o];
    const float be  = bbv[o];
    const float va1 = a1[m * 64 + o];
    const float va2 = a2[m * 64 + o];

    float h[8], sv[8], dv[8];
    #pragma unroll
    for (int k = 0; k < 8; ++k) h[k] = fmaf(ga, acc[k], be);

    #pragma unroll
    for (int k = 0; k < 8; ++k) {
        float s1 = h[k] * va1;
        float s2 = h[k] * va2;
        #pragma unroll
        for (int off = 1; off < 64; off <<= 1) {
            s1 += __shfl_xor(s1, off);
            s2 += __shfl_xor(s2, off);
        }
        sv[k] = s1; dv[k] = s2;
    }

    // tile store: tile jt = blockIdx.x, rows jj = wv*8..wv*8+7
    u32x4 upk;
    upk.x = pack_bf16(h[0], h[1]);
    upk.y = pack_bf16(h[2], h[3]);
    upk.z = pack_bf16(h[4], h[5]);
    upk.w = pack_bf16(h[6], h[7]);
    const size_t phys = ((size_t)(m * 128 + blockIdx.x)) * 4096 + o * 64 + wv * 16;
    *reinterpret_cast<u32x4*>(htb + phys) = upk;

    // sc / spq
    const int lk = o & 7;
    float ssel = sv[0], dsel = dv[0];
    #pragma unroll
    for (int k = 1; k < 8; ++k) {
        if (lk == k) { ssel = sv[k]; dsel = dv[k]; }
    }
    if (o < 8) {
        sc[(size_t)m * NN + n0 + lk] = exp2f(-0.8f * LOG2E * ssel);
    } else if (o < 16) {
        const float spv = dsel * LOG2E;
        float2 ex = make_float2(exp2f(spv), exp2f(0.2f * spv));
        *reinterpret_cast<float2*>(&spq[(size_t)(m * NN + n0 + lk) * 2]) = ex;
    }
}

// ---------- kernel 3: fused masked softmax + PV ----------
// grid (128, 4): x = i-tile (32 rows), y = mech. 256 thr = 4 waves = 4 j-windows
// of 1024 (32 tiles each). Each wave: 2 i-subtiles of 16, B ping-pong prefetch.
#define LOADT(tn, B) do {                                                  \
    const unsigned char* tb_ = tb0 + (size_t)(tn) * 4096;                  \
    B[0] = *reinterpret_cast<const s16x8*>(tb_);                           \
    B[1] = *reinterpret_cast<const s16x8*>(tb_ + 1024);                    \
    B[2] = *reinterpret_cast<const s16x8*>(tb_ + 2048);                    \
    B[3] = *reinterpret_cast<const s16x8*>(tb_ + 3072);                    \
} while (0)

#define COMPUTE(tn, B, mw0, mw1) do {                                      \
    const float* qp_ = pqb + (tn) * 64;                                    \
    const f32x4 q0_ = *reinterpret_cast<const f32x4*>(qp_);                \
    const f32x4 q1_ = *reinterpret_cast<const f32x4*>(qp_ + 4);            \
    const f32x4 q2_ = *reinterpret_cast<const f32x4*>(qp_ + 8);            \
    const f32x4 q3_ = *reinterpret_cast<const f32x4*>(qp_ + 12);           \
    const s16x8 Af0_ = mk_af(c0v, (mw0) >> sh, q0_, q1_, q2_, q3_, z0);    \
    const s16x8 Af1_ = mk_af(c1v, (mw1) >> sh, q0_, q1_, q2_, q3_, z1);    \
    acc0[0] = __builtin_amdgcn_mfma_f32_16x16x32_bf16(Af0_, B[0], acc0[0], 0, 0, 0); \
    acc0[1] = __builtin_amdgcn_mfma_f32_16x16x32_bf16(Af0_, B[1], acc0[1], 0, 0, 0); \
    acc0[2] = __builtin_amdgcn_mfma_f32_16x16x32_bf16(Af0_, B[2], acc0[2], 0, 0, 0); \
    acc0[3] = __builtin_amdgcn_mfma_f32_16x16x32_bf16(Af0_, B[3], acc0[3], 0, 0, 0); \
    acc1[0] = __builtin_amdgcn_mfma_f32_16x16x32_bf16(Af1_, B[0], acc1[0], 0, 0, 0); \
    acc1[1] = __builtin_amdgcn_mfma_f32_16x16x32_bf16(Af1_, B[1], acc1[1], 0, 0, 0); \
    acc1[2] = __builtin_amdgcn_mfma_f32_16x16x32_bf16(Af1_, B[2], acc1[2], 0, 0, 0); \
    acc1[3] = __builtin_amdgcn_mfma_f32_16x16x32_bf16(Af1_, B[3], acc1[3], 0, 0, 0); \
} while (0)

__global__ __launch_bounds__(256, 4) void k_attn(
    const unsigned int* __restrict__ msk, const float* __restrict__ sc,
    const float* __restrict__ spq, const unsigned char* __restrict__ htb,
    float* __restrict__ out)
{
    extern __shared__ float lds[];           // accP[4][2048] + zP[4][32]
    float* accP = lds;
    float* zP   = lds + 4 * 2048;

    const int t    = threadIdx.x;
    const int lane = t & 63;
    const int jq   = __builtin_amdgcn_readfirstlane(t >> 6); // wave = j-window 0..3
    const int col  = lane & 15;
    const int kg   = lane >> 4;
    const int sh   = kg * 8;
    const int i0   = blockIdx.x * 32;
    const int mech = blockIdx.y;

    const float c0v = sc[(size_t)mech * NN + i0 + col];
    const float c1v = sc[(size_t)mech * NN + i0 + 16 + col];

    const u32x4* mr0 = reinterpret_cast<const u32x4*>(
        msk + (size_t)(i0 + col) * 128 + jq * 32);
    const u32x4* mr1 = reinterpret_cast<const u32x4*>(
        msk + (size_t)(i0 + 16 + col) * 128 + jq * 32);
    const float* pqb = spq + (size_t)mech * NN * 2 + (jq * 1024 + kg * 8) * 2;
    const unsigned char* tb0 = htb + ((size_t)(mech * 128 + jq * 32)) * 4096
                             + col * 64 + kg * 16;

    f32x4 acc0[4], acc1[4];
    #pragma unroll
    for (int f = 0; f < 4; ++f) {
        acc0[f] = (f32x4){0.f, 0.f, 0.f, 0.f};
        acc1[f] = (f32x4){0.f, 0.f, 0.f, 0.f};
    }
    float z0 = 0.f, z1 = 0.f;

    s16x8 Ba[4], Bb[4];
    LOADT(0, Ba);
    u32x4 m0n = mr0[0];
    u32x4 m1n = mr1[0];

    #pragma unroll 1
    for (int tq = 0; tq < 8; ++tq) {
        const int base = tq * 4;
        const u32x4 m0 = m0n, m1 = m1n;
        if (tq < 7) { m0n = mr0[tq + 1]; m1n = mr1[tq + 1]; }
        LOADT(base + 1, Bb);
        COMPUTE(base + 0, Ba, m0[0], m1[0]);
        LOADT(base + 2, Ba);
        COMPUTE(base + 1, Bb, m0[1], m1[1]);
        LOADT(base + 3, Bb);
        COMPUTE(base + 2, Ba, m0[2], m1[2]);
        if (tq < 7) LOADT(base + 4, Ba);
        COMPUTE(base + 3, Bb, m0[3], m1[3]);
    }

    // row-sum Z: lanes {r, r+16, r+32, r+48} hold the same row
    z0 += __shfl_xor(z0, 16); z0 += __shfl_xor(z0, 32);
    z1 += __shfl_xor(z1, 16); z1 += __shfl_xor(z1, 32);

    // ---- epilogue: each wave writes its 8KB partial; parallel 4-way reduce ----
    float* my = accP + jq * 2048;
    #pragma unroll
    for (int f = 0; f < 4; ++f) {
        #pragma unroll
        for (int rr = 0; rr < 4; ++rr) {
            my[(kg * 4 + rr) * 64 + f * 16 + col]      = acc0[f][rr];
            my[(16 + kg * 4 + rr) * 64 + f * 16 + col] = acc1[f][rr];
        }
    }
    if (lane < 16) {
        zP[jq * 32 + lane]      = z0;
        zP[jq * 32 + 16 + lane] = z1;
    }
    __syncthreads();

    const int f0  = t * 8;             // 0..2040
    const int row = f0 >> 6;           // 0..31
    const int o0  = f0 & 63;
    f32x4 s0 = (f32x4){0.f, 0.f, 0.f, 0.f};
    f32x4 s1 = s0;
    float z = 0.f;
    #pragma unroll
    for (int p = 0; p < 4; ++p) {
        s0 += *reinterpret_cast<const f32x4*>(accP + p * 2048 + f0);
        s1 += *reinterpret_cast<const f32x4*>(accP + p * 2048 + f0 + 4);
        z  += zP[p * 32 + row];
    }
    const float inv = 1.0f / z;
    float res[8];
    #pragma unroll
    for (int e = 0; e < 4; ++e) {
        const float v0 = s0[e] * inv;
        const float v1 = s1[e] * inv;
        res[e]     = v0 > 0.f ? v0 : expm1f(v0);
        res[e + 4] = v1 > 0.f ? v1 : expm1f(v1);
    }
    float* op = out + (size_t)(i0 + row) * 256 + mech * 64 + o0;
    *reinterpret_cast<float4*>(op)     = make_float4(res[0], res[1], res[2], res[3]);
    *reinterpret_cast<float4*>(op + 4) = make_float4(res[4], res[5], res[6], res[7]);
}

extern "C" void kernel_launch(void* const* d_in, const int* in_sizes, int n_in,
                              void* d_out, int out_size, void* d_ws, size_t ws_size,
                              hipStream_t stream) {
    const float* x   = (const float*)d_in[0];
    const int*   adj = (const int*)d_in[1];
    const float* W   = (const float*)d_in[2];
    const float* a1  = (const float*)d_in[3];
    const float* a2  = (const float*)d_in[4];
    const float* Wc  = (const float*)d_in[5];
    const float* bc  = (const float*)d_in[6];
    float* out = (float*)d_out;

    float* wsf    = (float*)d_ws;
    float* part   = wsf;
    float* scv    = wsf + 16896;
    float* spq    = wsf + 33280;
    unsigned char* htb = (unsigned char*)(wsf + 66048);
    unsigned long long* msk = (unsigned long long*)(htb + (size_t)2097152);

    (void)hipFuncSetAttribute((const void*)k_attn,
                              hipFuncAttributeMaxDynamicSharedMemorySize, 33280);

    k_prep<<<1088, 256, 0, stream>>>(adj, msk, x, part);
    k_filmc<<<dim3(128, 4), 256, 0, stream>>>(x, W, a1, a2, part, Wc, bc, scv, spq, htb);
    k_attn<<<dim3(128, 4), 256, 33280, stream>>>((const unsigned int*)msk, scv, spq, htb, out);
}

// Round 13
// 98.286 us; speedup vs baseline: 1.0655x; 1.0655x over previous
//
#include <hip/hip_runtime.h>
#include <hip/hip_bf16.h>

// Problem constants
#define NN    4096
#define INS_  256
#define OUTS_ 64
#define MM    4
#define LOG2E 1.4426950408889634f

typedef float f32x4 __attribute__((ext_vector_type(4)));
typedef short s16x8 __attribute__((ext_vector_type(8)));
typedef unsigned int u32x4 __attribute__((ext_vector_type(4)));

typedef const __attribute__((address_space(1))) unsigned char glob_u8;
typedef __attribute__((address_space(3))) unsigned char lds_u8;

__device__ __forceinline__ void stage16(const void* g, void* l) {
    __builtin_amdgcn_global_load_lds((glob_u8*)g, (lds_u8*)l, 16, 0, 0);
}

__device__ __forceinline__ unsigned int cvt_pk_bf16(float a, float b) {
    unsigned int r;
    asm("v_cvt_pk_bf16_f32 %0, %1, %2" : "=v"(r) : "v"(a), "v"(b));
    return r;
}

// pack two f32 into bf16x2 (RNE) - used in k_filmc (not hot)
__device__ __forceinline__ unsigned int pack_bf16(float a, float b) {
    unsigned int ua = __builtin_bit_cast(unsigned int, a);
    unsigned int ub = __builtin_bit_cast(unsigned int, b);
    ua = (ua + 0x7FFFu + ((ua >> 16) & 1u)) >> 16;
    ub = (ub + 0x7FFFu + ((ub >> 16) & 1u)) & 0xFFFF0000u;
    return ua | ub;
}

// keep w if bit e of mb set, else 0  (sign-extend bit + and)
__device__ __forceinline__ float mand(float w, unsigned mb, int e) {
    const int m = ((int)(mb << (31 - e))) >> 31;
    return __builtin_bit_cast(float, (__builtin_bit_cast(int, w) & m));
}

// build A-fragment: 8 weights max(P, c*Q) masked, packed to bf16; accumulate f32 Z
__device__ __forceinline__ s16x8 mk_af(float c, unsigned mb,
        const f32x4 q0, const f32x4 q1, const f32x4 q2, const f32x4 q3, float& z) {
    const float w0 = mand(fmaxf(q0[0], c * q0[1]), mb, 0);
    const float w1 = mand(fmaxf(q0[2], c * q0[3]), mb, 1);
    const float w2 = mand(fmaxf(q1[0], c * q1[1]), mb, 2);
    const float w3 = mand(fmaxf(q1[2], c * q1[3]), mb, 3);
    const float w4 = mand(fmaxf(q2[0], c * q2[1]), mb, 4);
    const float w5 = mand(fmaxf(q2[2], c * q2[3]), mb, 5);
    const float w6 = mand(fmaxf(q3[0], c * q3[1]), mb, 6);
    const float w7 = mand(fmaxf(q3[2], c * q3[3]), mb, 7);
    z += ((w0 + w1) + (w2 + w3)) + ((w4 + w5) + (w6 + w7));
    u32x4 au;
    au.x = cvt_pk_bf16(w0, w1);
    au.y = cvt_pk_bf16(w2, w3);
    au.z = cvt_pk_bf16(w4, w5);
    au.w = cvt_pk_bf16(w6, w7);
    return __builtin_bit_cast(s16x8, au);
}

// ws layout (floats):
//   [0,16384)       part float [64][256]  (partial column sums)
//   [16896,33280)   sc  float [M][N]   = V/U = 2^{-0.8 s'}
//   [33280,66048)   spq float2[M][N]   = {2^{d'}, 2^{0.2 d'}}
//   byte 264192     Ht bf16 tiles [m][jt=0..127][4KB]: tile(o,jj) at o*64+jj*2  (2 MB)

// ---------- kernel 1: x column partial sums ----------
__global__ __launch_bounds__(256) void k_pool(const float* __restrict__ x,
                                              float* __restrict__ part) {
    const int t  = threadIdx.x;
    const int r0 = blockIdx.x * 64;
    float s = 0.f;
    #pragma unroll 8
    for (int r = 0; r < 64; ++r) s += x[(size_t)(r0 + r) * INS_ + t];
    part[blockIdx.x * INS_ + t] = s;
}

// ---------- kernel 2: fused conditioner + FiLM; emit tiled Ht, sc, spq ----------
__global__ __launch_bounds__(256, 2) void k_filmc(
    const float* __restrict__ x, const float* __restrict__ W,
    const float* __restrict__ a1, const float* __restrict__ a2,
    const float* __restrict__ part, const float* __restrict__ Wc,
    const float* __restrict__ bc, float* __restrict__ sc,
    float* __restrict__ spq, unsigned char* __restrict__ htb)
{
    __shared__ float wlds[INS_ * OUTS_];     // 64 KB: W[m] as [i][o]
    __shared__ float sp[INS_];
    __shared__ float pg[256];
    __shared__ float gg[64], bbv[64];

    const int t  = threadIdx.x;
    const int o  = t & 63;
    const int wv = __builtin_amdgcn_readfirstlane(t >> 6);   // wave 0..3
    const int m  = blockIdx.y;
    const int n0 = blockIdx.x * 32 + wv * 8;                 // this wave's 8 rows

    // async-stage W[m] (64 KB) into LDS: 16 x (256 thr x 16B)
    {
        const unsigned char* wsrc = (const unsigned char*)W + (size_t)m * 65536 + t * 16;
        unsigned char* wdst = (unsigned char*)wlds + t * 16;
        #pragma unroll
        for (int it = 0; it < 16; ++it)
            stage16(wsrc + it * 4096, wdst + it * 4096);
    }

    // conditioner: reduce partial column sums (all 256 threads)
    {
        float s = 0.f;
        #pragma unroll 8
        for (int b = 0; b < 64; ++b) s += part[b * INS_ + t];
        sp[t] = s * (1.0f / NN);
    }
    __syncthreads();   // sp ready (also drains W staging vmcnt)

    // split-K conditioner dot: 256 threads cover 128 outputs x 2 K-halves
    {
        const int half = t >> 7;            // 0/1
        const int idx  = t & 127;           // output index
        const int col  = m * 64 + (idx & 63) + ((idx & 64) ? 256 : 0);
        float acc = (half == 0) ? bc[col] : 0.f;
        const int ib = half * 128;
        #pragma unroll 8
        for (int i = 0; i < 128; ++i)
            acc = fmaf(sp[ib + i], Wc[(size_t)(ib + i) * 512 + col], acc);
        pg[t] = acc;
    }
    __syncthreads();
    if (t < 128) {
        const float v = pg[t] + pg[t + 128];
        if (t < 64) gg[t] = v; else bbv[t - 64] = v;
    }
    __syncthreads();

    // main x@W loop: wl from LDS (conflict-free), x rows via scalar loads
    float acc[8];
    #pragma unroll
    for (int k = 0; k < 8; ++k) acc[k] = 0.f;

    const float* xp = x + (size_t)n0 * INS_;

    #pragma unroll 4
    for (int i = 0; i < INS_; ++i) {
        const float wl = wlds[i * 64 + o];
        #pragma unroll
        for (int k = 0; k < 8; ++k)
            acc[k] = fmaf(xp[k * INS_ + i], wl, acc[k]);
    }

    const float ga  = gg[o];
    const float be  = bbv[o];
    const float va1 = a1[m * 64 + o];
    const float va2 = a2[m * 64 + o];

    float h[8], sv[8], dv[8];
    #pragma unroll
    for (int k = 0; k < 8; ++k) h[k] = fmaf(ga, acc[k], be);

    #pragma unroll
    for (int k = 0; k < 8; ++k) {
        float s1 = h[k] * va1;
        float s2 = h[k] * va2;
        #pragma unroll
        for (int off = 1; off < 64; off <<= 1) {
            s1 += __shfl_xor(s1, off);
            s2 += __shfl_xor(s2, off);
        }
        sv[k] = s1; dv[k] = s2;
    }

    // tile store: tile jt = blockIdx.x, rows jj = wv*8..wv*8+7
    u32x4 upk;
    upk.x = pack_bf16(h[0], h[1]);
    upk.y = pack_bf16(h[2], h[3]);
    upk.z = pack_bf16(h[4], h[5]);
    upk.w = pack_bf16(h[6], h[7]);
    const size_t phys = ((size_t)(m * 128 + blockIdx.x)) * 4096 + o * 64 + wv * 16;
    *reinterpret_cast<u32x4*>(htb + phys) = upk;

    // sc / spq
    const int lk = o & 7;
    float ssel = sv[0], dsel = dv[0];
    #pragma unroll
    for (int k = 1; k < 8; ++k) {
        if (lk == k) { ssel = sv[k]; dsel = dv[k]; }
    }
    if (o < 8) {
        sc[(size_t)m * NN + n0 + lk] = exp2f(-0.8f * LOG2E * ssel);
    } else if (o < 16) {
        const float spv = dsel * LOG2E;
        float2 ex = make_float2(exp2f(spv), exp2f(0.2f * spv));
        *reinterpret_cast<float2*>(&spq[(size_t)(m * NN + n0 + lk) * 2]) = ex;
    }
}

// ---------- kernel 3: fused adj-pack + masked softmax + PV ----------
// grid 256: block = 16 i-rows (i0 = b*16), ALL 4 mechs, full j.
// 1024 thr = 16 waves = (jq 0..3) x (mech 0..3); wave j-window = jq*1024..+1024.
// Phase A: wave w ballot-packs raw adj row i0+w into LDS bitmask (adj read ONCE).
// Phase B: r12-proven attn loop, masks from LDS. Epilogue: 4-way jq reduce.
#define MROWW 132   // u32 words per mask row (128 + pad; 528B, 16B-aligned)

#define LOADT(tn, B) do {                                                  \
    const unsigned char* tb_ = tb0 + (size_t)(tn) * 4096;                  \
    B[0] = *reinterpret_cast<const s16x8*>(tb_);                           \
    B[1] = *reinterpret_cast<const s16x8*>(tb_ + 1024);                    \
    B[2] = *reinterpret_cast<const s16x8*>(tb_ + 2048);                    \
    B[3] = *reinterpret_cast<const s16x8*>(tb_ + 3072);                    \
} while (0)

#define COMPUTE1(tn, B, mw) do {                                           \
    const float* qp_ = pqb + (tn) * 64;                                    \
    const f32x4 q0_ = *reinterpret_cast<const f32x4*>(qp_);                \
    const f32x4 q1_ = *reinterpret_cast<const f32x4*>(qp_ + 4);            \
    const f32x4 q2_ = *reinterpret_cast<const f32x4*>(qp_ + 8);            \
    const f32x4 q3_ = *reinterpret_cast<const f32x4*>(qp_ + 12);           \
    const s16x8 Af_ = mk_af(c0v, (mw) >> sh, q0_, q1_, q2_, q3_, z0);      \
    acc[0] = __builtin_amdgcn_mfma_f32_16x16x32_bf16(Af_, B[0], acc[0], 0, 0, 0); \
    acc[1] = __builtin_amdgcn_mfma_f32_16x16x32_bf16(Af_, B[1], acc[1], 0, 0, 0); \
    acc[2] = __builtin_amdgcn_mfma_f32_16x16x32_bf16(Af_, B[2], acc[2], 0, 0, 0); \
    acc[3] = __builtin_amdgcn_mfma_f32_16x16x32_bf16(Af_, B[3], acc[3], 0, 0, 0); \
} while (0)

__global__ __launch_bounds__(1024, 1) void k_attn(
    const int* __restrict__ adj, const float* __restrict__ sc,
    const float* __restrict__ spq, const unsigned char* __restrict__ htb,
    float* __restrict__ out)
{
    extern __shared__ unsigned char dlds[];
    unsigned int* mlds = (unsigned int*)dlds;              // [16][MROWW] = 8448 B
    float* accP = (float*)(dlds + 8448);                   // [16][16][64] = 64 KB
    float* zP   = (float*)(dlds + 8448 + 65536);           // [16][16]

    const int t    = threadIdx.x;
    const int lane = t & 63;
    const int w    = __builtin_amdgcn_readfirstlane(t >> 6);   // wave 0..15
    const int mech = w & 3;
    const int jq   = w >> 2;          // 0..3
    const int col  = lane & 15;
    const int kg   = lane >> 4;
    const int sh   = kg * 8;
    const int i0   = blockIdx.x * 16;

    // ---------- Phase A: pack adj row (i0 + w) into LDS bitmask ----------
    {
        const int* __restrict__ row = adj + (size_t)(i0 + w) * NN;
        unsigned int* mrow = mlds + w * MROWW;
        #pragma unroll 1
        for (int c0 = 0; c0 < 64; c0 += 16) {
            int a[16];
            #pragma unroll
            for (int k = 0; k < 16; ++k) a[k] = row[(c0 + k) * 64 + lane];
            unsigned long long m[16];
            #pragma unroll
            for (int k = 0; k < 16; ++k) m[k] = __ballot(a[k] != 0);
            if (lane == 0) {
                #pragma unroll
                for (int k = 0; k < 16; ++k)
                    *reinterpret_cast<unsigned long long*>(mrow + (c0 + k) * 2) = m[k];
            }
        }
    }
    __syncthreads();

    // ---------- Phase B: masked softmax + PV over (mech, j-window jq) ----------
    const float c0v = sc[(size_t)mech * NN + i0 + col];
    const u32x4* mr0 = reinterpret_cast<const u32x4*>(mlds + col * MROWW + jq * 32);
    const float* pqb = spq + (size_t)mech * NN * 2 + (jq * 1024 + kg * 8) * 2;
    const unsigned char* tb0 = htb + ((size_t)(mech * 128 + jq * 32)) * 4096
                             + col * 64 + kg * 16;

    f32x4 acc[4];
    #pragma unroll
    for (int f = 0; f < 4; ++f) acc[f] = (f32x4){0.f, 0.f, 0.f, 0.f};
    float z0 = 0.f;

    s16x8 Ba[4], Bb[4];
    LOADT(0, Ba);

    #pragma unroll 1
    for (int tq = 0; tq < 8; ++tq) {
        const int base = tq * 4;
        const u32x4 m0 = mr0[tq];
        LOADT(base + 1, Bb);
        COMPUTE1(base + 0, Ba, m0[0]);
        LOADT(base + 2, Ba);
        COMPUTE1(base + 1, Bb, m0[1]);
        LOADT(base + 3, Bb);
        COMPUTE1(base + 2, Ba, m0[2]);
        if (tq < 7) LOADT(base + 4, Ba);
        COMPUTE1(base + 3, Bb, m0[3]);
    }

    // row-sum Z: lanes {r, r+16, r+32, r+48} hold the same row
    z0 += __shfl_xor(z0, 16); z0 += __shfl_xor(z0, 32);

    // ---- epilogue: each wave writes its 4KB partial; 4-way jq reduce ----
    float* my = accP + w * 1024;
    #pragma unroll
    for (int f = 0; f < 4; ++f) {
        #pragma unroll
        for (int rr = 0; rr < 4; ++rr)
            my[(kg * 4 + rr) * 64 + f * 16 + col] = acc[f][rr];
    }
    if (lane < 16) zP[w * 16 + lane] = z0;
    __syncthreads();

    const int f0    = t * 4;           // 0..4092
    const int row   = f0 >> 8;         // 0..15
    const int mo    = f0 & 255;
    const int mech2 = mo >> 6;
    const int o0    = mo & 63;
    f32x4 s = (f32x4){0.f, 0.f, 0.f, 0.f};
    float z = 0.f;
    #pragma unroll
    for (int p = 0; p < 4; ++p) {
        const int wp = p * 4 + mech2;
        s += *reinterpret_cast<const f32x4*>(accP + wp * 1024 + row * 64 + o0);
        z += zP[wp * 16 + row];
    }
    const float inv = 1.0f / z;
    f32x4 res;
    #pragma unroll
    for (int e = 0; e < 4; ++e) {
        const float v = s[e] * inv;
        res[e] = v > 0.f ? v : expm1f(v);
    }
    *reinterpret_cast<f32x4*>(out + (size_t)(i0 + row) * 256 + mo) = res;
}

extern "C" void kernel_launch(void* const* d_in, const int* in_sizes, int n_in,
                              void* d_out, int out_size, void* d_ws, size_t ws_size,
                              hipStream_t stream) {
    const float* x   = (const float*)d_in[0];
    const int*   adj = (const int*)d_in[1];
    const float* W   = (const float*)d_in[2];
    const float* a1  = (const float*)d_in[3];
    const float* a2  = (const float*)d_in[4];
    const float* Wc  = (const float*)d_in[5];
    const float* bc  = (const float*)d_in[6];
    float* out = (float*)d_out;

    float* wsf    = (float*)d_ws;
    float* part   = wsf;
    float* scv    = wsf + 16896;
    float* spq    = wsf + 33280;
    unsigned char* htb = (unsigned char*)(wsf + 66048);

    (void)hipFuncSetAttribute((const void*)k_attn,
                              hipFuncAttributeMaxDynamicSharedMemorySize, 75008);

    k_pool<<<64, 256, 0, stream>>>(x, part);
    k_filmc<<<dim3(128, 4), 256, 0, stream>>>(x, W, a1, a2, part, Wc, bc, scv, spq, htb);
    k_attn<<<256, 1024, 75008, stream>>>(adj, scv, spq, htb, out);
}

// Round 14
// 73.310 us; speedup vs baseline: 1.4285x; 1.3407x over previous
//
#include <hip/hip_runtime.h>
#include <hip/hip_bf16.h>

// Problem constants
#define NN    4096
#define INS_  256
#define OUTS_ 64
#define MM    4
#define LOG2E 1.4426950408889634f

typedef float f32x4 __attribute__((ext_vector_type(4)));
typedef short s16x8 __attribute__((ext_vector_type(8)));
typedef unsigned int u32x4 __attribute__((ext_vector_type(4)));

typedef const __attribute__((address_space(1))) unsigned char glob_u8;
typedef __attribute__((address_space(3))) unsigned char lds_u8;

__device__ __forceinline__ void stage16(const void* g, void* l) {
    __builtin_amdgcn_global_load_lds((glob_u8*)g, (lds_u8*)l, 16, 0, 0);
}

__device__ __forceinline__ unsigned int cvt_pk_bf16(float a, float b) {
    unsigned int r;
    asm("v_cvt_pk_bf16_f32 %0, %1, %2" : "=v"(r) : "v"(a), "v"(b));
    return r;
}

// pack two f32 into bf16x2 (RNE) - used in k_filmc (not hot)
__device__ __forceinline__ unsigned int pack_bf16(float a, float b) {
    unsigned int ua = __builtin_bit_cast(unsigned int, a);
    unsigned int ub = __builtin_bit_cast(unsigned int, b);
    ua = (ua + 0x7FFFu + ((ua >> 16) & 1u)) >> 16;
    ub = (ub + 0x7FFFu + ((ub >> 16) & 1u)) & 0xFFFF0000u;
    return ua | ub;
}

// keep w if bit e of mb set, else 0  (sign-extend bit + and)
__device__ __forceinline__ float mand(float w, unsigned mb, int e) {
    const int m = ((int)(mb << (31 - e))) >> 31;
    return __builtin_bit_cast(float, (__builtin_bit_cast(int, w) & m));
}

// build A-fragment: 8 weights max(P, c*Q) masked, packed to bf16; accumulate f32 Z
__device__ __forceinline__ s16x8 mk_af(float c, unsigned mb,
        const f32x4 q0, const f32x4 q1, const f32x4 q2, const f32x4 q3, float& z) {
    const float w0 = mand(fmaxf(q0[0], c * q0[1]), mb, 0);
    const float w1 = mand(fmaxf(q0[2], c * q0[3]), mb, 1);
    const float w2 = mand(fmaxf(q1[0], c * q1[1]), mb, 2);
    const float w3 = mand(fmaxf(q1[2], c * q1[3]), mb, 3);
    const float w4 = mand(fmaxf(q2[0], c * q2[1]), mb, 4);
    const float w5 = mand(fmaxf(q2[2], c * q2[3]), mb, 5);
    const float w6 = mand(fmaxf(q3[0], c * q3[1]), mb, 6);
    const float w7 = mand(fmaxf(q3[2], c * q3[3]), mb, 7);
    z += ((w0 + w1) + (w2 + w3)) + ((w4 + w5) + (w6 + w7));
    u32x4 au;
    au.x = cvt_pk_bf16(w0, w1);
    au.y = cvt_pk_bf16(w2, w3);
    au.z = cvt_pk_bf16(w4, w5);
    au.w = cvt_pk_bf16(w6, w7);
    return __builtin_bit_cast(s16x8, au);
}

// ws layout (floats):
//   [0,16384)       part float [64][256]  (partial column sums)
//   [16896,33280)   sc  float [M][N]   = V/U = 2^{-0.8 s'}
//   [33280,66048)   spq float2[M][N]   = {2^{d'}, 2^{0.2 d'}}
//   byte 264192     Ht bf16 tiles [m][jt=0..127][4KB]: tile(o,jj) at o*64+jj*2  (2 MB)
//   byte 2361344    adj bitmask [N][512B]                                       (2 MB)

// ---------- kernel 1: fused adj->bitmask pack (blocks 0..1023) + x column
//            partial sums (blocks 1024..1087) ----------
__global__ __launch_bounds__(256) void k_prep(const int* __restrict__ adj,
                                              unsigned long long* __restrict__ msk,
                                              const float* __restrict__ x,
                                              float* __restrict__ part) {
    const int b = blockIdx.x;
    if (b < 1024) {
        const int lane = threadIdx.x & 63;
        const int w    = threadIdx.x >> 6;
        const int r    = b * 4 + w;
        const int* __restrict__ row = adj + (size_t)r * NN;
        unsigned long long* mrow = msk + (size_t)r * 64;
        #pragma unroll 1
        for (int c0 = 0; c0 < 64; c0 += 16) {
            int a[16];
            #pragma unroll
            for (int k = 0; k < 16; ++k) a[k] = row[(c0 + k) * 64 + lane];
            unsigned long long m[16];
            #pragma unroll
            for (int k = 0; k < 16; ++k) m[k] = __ballot(a[k] != 0);
            if (lane == 0) {
                #pragma unroll
                for (int k = 0; k < 16; ++k) mrow[c0 + k] = m[k];
            }
        }
    } else {
        const int bb = b - 1024;
        const int t  = threadIdx.x;
        const int r0 = bb * 64;
        float s = 0.f;
        #pragma unroll 8
        for (int r = 0; r < 64; ++r) s += x[(size_t)(r0 + r) * INS_ + t];
        part[bb * INS_ + t] = s;
    }
}

// ---------- kernel 2: fused conditioner + FiLM; emit tiled Ht, sc, spq ----------
__global__ __launch_bounds__(256, 2) void k_filmc(
    const float* __restrict__ x, const float* __restrict__ W,
    const float* __restrict__ a1, const float* __restrict__ a2,
    const float* __restrict__ part, const float* __restrict__ Wc,
    const float* __restrict__ bc, float* __restrict__ sc,
    float* __restrict__ spq, unsigned char* __restrict__ htb)
{
    __shared__ float wlds[INS_ * OUTS_];     // 64 KB: W[m] as [i][o]
    __shared__ float sp[INS_];
    __shared__ float pg[256];
    __shared__ float gg[64], bbv[64];

    const int t  = threadIdx.x;
    const int o  = t & 63;
    const int wv = __builtin_amdgcn_readfirstlane(t >> 6);   // wave 0..3
    const int m  = blockIdx.y;
    const int n0 = blockIdx.x * 32 + wv * 8;                 // this wave's 8 rows

    // async-stage W[m] (64 KB) into LDS: 16 x (256 thr x 16B)
    {
        const unsigned char* wsrc = (const unsigned char*)W + (size_t)m * 65536 + t * 16;
        unsigned char* wdst = (unsigned char*)wlds + t * 16;
        #pragma unroll
        for (int it = 0; it < 16; ++it)
            stage16(wsrc + it * 4096, wdst + it * 4096);
    }

    // conditioner: reduce partial column sums (all 256 threads)
    {
        float s = 0.f;
        #pragma unroll 8
        for (int b = 0; b < 64; ++b) s += part[b * INS_ + t];
        sp[t] = s * (1.0f / NN);
    }
    __syncthreads();   // sp ready (also drains W staging vmcnt)

    // split-K conditioner dot: 256 threads cover 128 outputs x 2 K-halves
    {
        const int half = t >> 7;            // 0/1
        const int idx  = t & 127;           // output index
        const int col  = m * 64 + (idx & 63) + ((idx & 64) ? 256 : 0);
        float acc = (half == 0) ? bc[col] : 0.f;
        const int ib = half * 128;
        #pragma unroll 8
        for (int i = 0; i < 128; ++i)
            acc = fmaf(sp[ib + i], Wc[(size_t)(ib + i) * 512 + col], acc);
        pg[t] = acc;
    }
    __syncthreads();
    if (t < 128) {
        const float v = pg[t] + pg[t + 128];
        if (t < 64) gg[t] = v; else bbv[t - 64] = v;
    }
    __syncthreads();

    // main x@W loop: wl from LDS (conflict-free), x rows via scalar loads
    float acc[8];
    #pragma unroll
    for (int k = 0; k < 8; ++k) acc[k] = 0.f;

    const float* xp = x + (size_t)n0 * INS_;

    #pragma unroll 4
    for (int i = 0; i < INS_; ++i) {
        const float wl = wlds[i * 64 + o];
        #pragma unroll
        for (int k = 0; k < 8; ++k)
            acc[k] = fmaf(xp[k * INS_ + i], wl, acc[k]);
    }

    const float ga  = gg[o];
    const float be  = bbv[o];
    const float va1 = a1[m * 64 + o];
    const float va2 = a2[m * 64 + o];

    float h[8], sv[8], dv[8];
    #pragma unroll
    for (int k = 0; k < 8; ++k) h[k] = fmaf(ga, acc[k], be);

    #pragma unroll
    for (int k = 0; k < 8; ++k) {
        float s1 = h[k] * va1;
        float s2 = h[k] * va2;
        #pragma unroll
        for (int off = 1; off < 64; off <<= 1) {
            s1 += __shfl_xor(s1, off);
            s2 += __shfl_xor(s2, off);
        }
        sv[k] = s1; dv[k] = s2;
    }

    // tile store: tile jt = blockIdx.x, rows jj = wv*8..wv*8+7
    u32x4 upk;
    upk.x = pack_bf16(h[0], h[1]);
    upk.y = pack_bf16(h[2], h[3]);
    upk.z = pack_bf16(h[4], h[5]);
    upk.w = pack_bf16(h[6], h[7]);
    const size_t phys = ((size_t)(m * 128 + blockIdx.x)) * 4096 + o * 64 + wv * 16;
    *reinterpret_cast<u32x4*>(htb + phys) = upk;

    // sc / spq
    const int lk = o & 7;
    float ssel = sv[0], dsel = dv[0];
    #pragma unroll
    for (int k = 1; k < 8; ++k) {
        if (lk == k) { ssel = sv[k]; dsel = dv[k]; }
    }
    if (o < 8) {
        sc[(size_t)m * NN + n0 + lk] = exp2f(-0.8f * LOG2E * ssel);
    } else if (o < 16) {
        const float spv = dsel * LOG2E;
        float2 ex = make_float2(exp2f(spv), exp2f(0.2f * spv));
        *reinterpret_cast<float2*>(&spq[(size_t)(m * NN + n0 + lk) * 2]) = ex;
    }
}

// ---------- kernel 3: fused masked softmax + PV, 4-subtile B-reuse ----------
// grid (64, 4): x = i-tile (64 rows), y = mech. 512 thr = 8 waves = 8 j-windows
// of 512 (16 tiles). Each wave: 4 i-subtiles of 16 sharing every B-tile load.
#define LOADT(tn, B) do {                                                  \
    const unsigned char* tb_ = tb0 + (size_t)(tn) * 4096;                  \
    B[0] = *reinterpret_cast<const s16x8*>(tb_);                           \
    B[1] = *reinterpret_cast<const s16x8*>(tb_ + 1024);                    \
    B[2] = *reinterpret_cast<const s16x8*>(tb_ + 2048);                    \
    B[3] = *reinterpret_cast<const s16x8*>(tb_ + 3072);                    \
} while (0)

#define COMPUTE4(tn, B, w0_, w1_, w2_, w3_) do {                           \
    const float* qp_ = pqb + (tn) * 64;                                    \
    const f32x4 q0_ = *reinterpret_cast<const f32x4*>(qp_);                \
    const f32x4 q1_ = *reinterpret_cast<const f32x4*>(qp_ + 4);            \
    const f32x4 q2_ = *reinterpret_cast<const f32x4*>(qp_ + 8);            \
    const f32x4 q3_ = *reinterpret_cast<const f32x4*>(qp_ + 12);           \
    const s16x8 A0_ = mk_af(c0v, (w0_) >> sh, q0_, q1_, q2_, q3_, z0);     \
    const s16x8 A1_ = mk_af(c1v, (w1_) >> sh, q0_, q1_, q2_, q3_, z1);     \
    const s16x8 A2_ = mk_af(c2v, (w2_) >> sh, q0_, q1_, q2_, q3_, z2);     \
    const s16x8 A3_ = mk_af(c3v, (w3_) >> sh, q0_, q1_, q2_, q3_, z3);     \
    acc0[0] = __builtin_amdgcn_mfma_f32_16x16x32_bf16(A0_, B[0], acc0[0], 0, 0, 0); \
    acc0[1] = __builtin_amdgcn_mfma_f32_16x16x32_bf16(A0_, B[1], acc0[1], 0, 0, 0); \
    acc0[2] = __builtin_amdgcn_mfma_f32_16x16x32_bf16(A0_, B[2], acc0[2], 0, 0, 0); \
    acc0[3] = __builtin_amdgcn_mfma_f32_16x16x32_bf16(A0_, B[3], acc0[3], 0, 0, 0); \
    acc1[0] = __builtin_amdgcn_mfma_f32_16x16x32_bf16(A1_, B[0], acc1[0], 0, 0, 0); \
    acc1[1] = __builtin_amdgcn_mfma_f32_16x16x32_bf16(A1_, B[1], acc1[1], 0, 0, 0); \
    acc1[2] = __builtin_amdgcn_mfma_f32_16x16x32_bf16(A1_, B[2], acc1[2], 0, 0, 0); \
    acc1[3] = __builtin_amdgcn_mfma_f32_16x16x32_bf16(A1_, B[3], acc1[3], 0, 0, 0); \
    acc2[0] = __builtin_amdgcn_mfma_f32_16x16x32_bf16(A2_, B[0], acc2[0], 0, 0, 0); \
    acc2[1] = __builtin_amdgcn_mfma_f32_16x16x32_bf16(A2_, B[1], acc2[1], 0, 0, 0); \
    acc2[2] = __builtin_amdgcn_mfma_f32_16x16x32_bf16(A2_, B[2], acc2[2], 0, 0, 0); \
    acc2[3] = __builtin_amdgcn_mfma_f32_16x16x32_bf16(A2_, B[3], acc2[3], 0, 0, 0); \
    acc3[0] = __builtin_amdgcn_mfma_f32_16x16x32_bf16(A3_, B[0], acc3[0], 0, 0, 0); \
    acc3[1] = __builtin_amdgcn_mfma_f32_16x16x32_bf16(A3_, B[1], acc3[1], 0, 0, 0); \
    acc3[2] = __builtin_amdgcn_mfma_f32_16x16x32_bf16(A3_, B[2], acc3[2], 0, 0, 0); \
    acc3[3] = __builtin_amdgcn_mfma_f32_16x16x32_bf16(A3_, B[3], acc3[3], 0, 0, 0); \
} while (0)

__global__ __launch_bounds__(512, 2) void k_attn(
    const unsigned int* __restrict__ msk, const float* __restrict__ sc,
    const float* __restrict__ spq, const unsigned char* __restrict__ htb,
    float* __restrict__ out)
{
    extern __shared__ float lds[];           // accP[4][64*64] + zP[8][64]
    float* accP = lds;                       // 65536 B
    float* zP   = lds + 4 * 4096;            // 2048 B

    const int t    = threadIdx.x;
    const int lane = t & 63;
    const int jq   = __builtin_amdgcn_readfirstlane(t >> 6); // wave = j-window 0..7
    const int col  = lane & 15;
    const int kg   = lane >> 4;
    const int sh   = kg * 8;
    const int i0   = blockIdx.x * 64;
    const int mech = blockIdx.y;

    const float c0v = sc[(size_t)mech * NN + i0 + col];
    const float c1v = sc[(size_t)mech * NN + i0 + 16 + col];
    const float c2v = sc[(size_t)mech * NN + i0 + 32 + col];
    const float c3v = sc[(size_t)mech * NN + i0 + 48 + col];

    const u32x4* mr0 = reinterpret_cast<const u32x4*>(
        msk + (size_t)(i0 + col) * 128 + jq * 16);
    const u32x4* mr1 = reinterpret_cast<const u32x4*>(
        msk + (size_t)(i0 + 16 + col) * 128 + jq * 16);
    const u32x4* mr2 = reinterpret_cast<const u32x4*>(
        msk + (size_t)(i0 + 32 + col) * 128 + jq * 16);
    const u32x4* mr3 = reinterpret_cast<const u32x4*>(
        msk + (size_t)(i0 + 48 + col) * 128 + jq * 16);
    const float* pqb = spq + (size_t)mech * NN * 2 + (jq * 512 + kg * 8) * 2;
    const unsigned char* tb0 = htb + ((size_t)(mech * 128 + jq * 16)) * 4096
                             + col * 64 + kg * 16;

    f32x4 acc0[4], acc1[4], acc2[4], acc3[4];
    #pragma unroll
    for (int f = 0; f < 4; ++f) {
        acc0[f] = (f32x4){0.f, 0.f, 0.f, 0.f};
        acc1[f] = acc0[f]; acc2[f] = acc0[f]; acc3[f] = acc0[f];
    }
    float z0 = 0.f, z1 = 0.f, z2 = 0.f, z3 = 0.f;

    s16x8 Ba[4], Bb[4];
    LOADT(0, Ba);
    u32x4 m0n = mr0[0], m1n = mr1[0], m2n = mr2[0], m3n = mr3[0];

    #pragma unroll 1
    for (int tq = 0; tq < 4; ++tq) {
        const int base = tq * 4;
        const u32x4 m0 = m0n, m1 = m1n, m2 = m2n, m3 = m3n;
        if (tq < 3) { m0n = mr0[tq + 1]; m1n = mr1[tq + 1];
                      m2n = mr2[tq + 1]; m3n = mr3[tq + 1]; }
        LOADT(base + 1, Bb);
        COMPUTE4(base + 0, Ba, m0[0], m1[0], m2[0], m3[0]);
        LOADT(base + 2, Ba);
        COMPUTE4(base + 1, Bb, m0[1], m1[1], m2[1], m3[1]);
        LOADT(base + 3, Bb);
        COMPUTE4(base + 2, Ba, m0[2], m1[2], m2[2], m3[2]);
        if (tq < 3) LOADT(base + 4, Ba);
        COMPUTE4(base + 3, Bb, m0[3], m1[3], m2[3], m3[3]);
    }

    // row-sum Z: lanes {r, r+16, r+32, r+48} hold the same row
    z0 += __shfl_xor(z0, 16); z0 += __shfl_xor(z0, 32);
    z1 += __shfl_xor(z1, 16); z1 += __shfl_xor(z1, 32);
    z2 += __shfl_xor(z2, 16); z2 += __shfl_xor(z2, 32);
    z3 += __shfl_xor(z3, 16); z3 += __shfl_xor(z3, 32);

    // ---- epilogue: 2-phase jq-pair accumulate into accP[4][64][64] ----
    if (lane < 16) {
        zP[jq * 64 +      lane] = z0;
        zP[jq * 64 + 16 + lane] = z1;
        zP[jq * 64 + 32 + lane] = z2;
        zP[jq * 64 + 48 + lane] = z3;
    }
    float* my = accP + (jq & 3) * 4096;
    if (jq < 4) {
        #pragma unroll
        for (int f = 0; f < 4; ++f) {
            #pragma unroll
            for (int rr = 0; rr < 4; ++rr) {
                const int ro = (kg * 4 + rr) * 64 + f * 16 + col;
                my[ro]            = acc0[f][rr];
                my[1024 + ro]     = acc1[f][rr];
                my[2048 + ro]     = acc2[f][rr];
                my[3072 + ro]     = acc3[f][rr];
            }
        }
    }
    __syncthreads();
    if (jq >= 4) {
        #pragma unroll
        for (int f = 0; f < 4; ++f) {
            #pragma unroll
            for (int rr = 0; rr < 4; ++rr) {
                const int ro = (kg * 4 + rr) * 64 + f * 16 + col;
                my[ro]        += acc0[f][rr];
                my[1024 + ro] += acc1[f][rr];
                my[2048 + ro] += acc2[f][rr];
                my[3072 + ro] += acc3[f][rr];
            }
        }
    }
    __syncthreads();

    // final: 512 threads x 8 outputs = 64 rows x 64 cols
    const int f0  = t * 8;             // 0..4088
    const int row = f0 >> 6;           // 0..63
    const int o0  = f0 & 63;
    f32x4 s0 = (f32x4){0.f, 0.f, 0.f, 0.f};
    f32x4 s1 = s0;
    float z = 0.f;
    #pragma unroll
    for (int p = 0; p < 4; ++p) {
        s0 += *reinterpret_cast<const f32x4*>(accP + p * 4096 + f0);
        s1 += *reinterpret_cast<const f32x4*>(accP + p * 4096 + f0 + 4);
    }
    #pragma unroll
    for (int q = 0; q < 8; ++q) z += zP[q * 64 + row];
    const float inv = 1.0f / z;
    float res[8];
    #pragma unroll
    for (int e = 0; e < 4; ++e) {
        const float v0 = s0[e] * inv;
        const float v1 = s1[e] * inv;
        res[e]     = v0 > 0.f ? v0 : expm1f(v0);
        res[e + 4] = v1 > 0.f ? v1 : expm1f(v1);
    }
    float* op = out + (size_t)(i0 + row) * 256 + mech * 64 + o0;
    *reinterpret_cast<float4*>(op)     = make_float4(res[0], res[1], res[2], res[3]);
    *reinterpret_cast<float4*>(op + 4) = make_float4(res[4], res[5], res[6], res[7]);
}

extern "C" void kernel_launch(void* const* d_in, const int* in_sizes, int n_in,
                              void* d_out, int out_size, void* d_ws, size_t ws_size,
                              hipStream_t stream) {
    const float* x   = (const float*)d_in[0];
    const int*   adj = (const int*)d_in[1];
    const float* W   = (const float*)d_in[2];
    const float* a1  = (const float*)d_in[3];
    const float* a2  = (const float*)d_in[4];
    const float* Wc  = (const float*)d_in[5];
    const float* bc  = (const float*)d_in[6];
    float* out = (float*)d_out;

    float* wsf    = (float*)d_ws;
    float* part   = wsf;
    float* scv    = wsf + 16896;
    float* spq    = wsf + 33280;
    unsigned char* htb = (unsigned char*)(wsf + 66048);
    unsigned long long* msk = (unsigned long long*)(htb + (size_t)2097152);

    (void)hipFuncSetAttribute((const void*)k_attn,
                              hipFuncAttributeMaxDynamicSharedMemorySize, 67584);

    k_prep<<<1088, 256, 0, stream>>>(adj, msk, x, part);
    k_filmc<<<dim3(128, 4), 256, 0, stream>>>(x, W, a1, a2, part, Wc, bc, scv, spq, htb);
    k_attn<<<dim3(64, 4), 512, 67584, stream>>>((const unsigned int*)msk, scv, spq, htb, out);
}